// Round 1
// baseline (542.852 us; speedup 1.0000x reference)
//
#include <hip/hip_runtime.h>
#include <math.h>

#define TM 64          // rows per block
#define TN 128         // 2*E columns (route | noise)
#define BK 32          // k-tile
#define NEXP 64
#define XS_STRIDE (TM + 4)   // 68: keeps rows 16B-aligned, breaks bank stride
#define WS_STRIDE (TN + 4)   // 132
#define L_STRIDE  (TN + 4)   // 132

__device__ __forceinline__ float softplus_f(float x) {
    // stable: max(x,0) + log1p(exp(-|x|))
    return fmaxf(x, 0.0f) + log1pf(expf(-fabsf(x)));
}

__global__ __launch_bounds__(256, 2)
void noisy_topk_router_kernel(const float* __restrict__ x,
                              const float* __restrict__ Wr,
                              const float* __restrict__ br,
                              const float* __restrict__ Wn,
                              const float* __restrict__ bn,
                              const float* __restrict__ eps,
                              float* __restrict__ out,
                              int N, int D) {
    __shared__ union alignas(16) {
        struct {
            float Xs[BK][XS_STRIDE];   // [k][row]
            float Ws[BK][WS_STRIDE];   // [k][col]  col<64: route, col>=64: noise
        } st;
        float L[TM][L_STRIDE];         // logits for epilogue
    } sm;
    __shared__ float p1s[TM], p2s[TM];
    __shared__ int   i1s[TM], i2s[TM];

    const int tid = threadIdx.x;
    const int rowbase = blockIdx.x * TM;

    // compute-phase mapping: 8 rows x 4 cols per thread
    const int r0 = (tid >> 5) * 8;   // 0,8,...,56
    const int c0 = (tid & 31) * 4;   // 0,4,...,124

    float acc[8][4];
#pragma unroll
    for (int i = 0; i < 8; ++i)
#pragma unroll
        for (int j = 0; j < 4; ++j) acc[i][j] = 0.0f;

    // staging mapping: q = float4 slot within BK, rr = row/expert
    const int q  = tid & 7;    // 0..7  -> k offset q*4
    const int rr = tid >> 3;   // 0..31

    for (int k0 = 0; k0 < D; k0 += BK) {
#pragma unroll
        for (int i = 0; i < 2; ++i) {
            const int row = rr + 32 * i;  // 0..63
            const float4 xv = *(const float4*)&x[(size_t)(rowbase + row) * D + k0 + q * 4];
            sm.st.Xs[q * 4 + 0][row] = xv.x;
            sm.st.Xs[q * 4 + 1][row] = xv.y;
            sm.st.Xs[q * 4 + 2][row] = xv.z;
            sm.st.Xs[q * 4 + 3][row] = xv.w;
            const float4 wv = *(const float4*)&Wr[(size_t)row * D + k0 + q * 4];
            sm.st.Ws[q * 4 + 0][row] = wv.x;
            sm.st.Ws[q * 4 + 1][row] = wv.y;
            sm.st.Ws[q * 4 + 2][row] = wv.z;
            sm.st.Ws[q * 4 + 3][row] = wv.w;
            const float4 nv = *(const float4*)&Wn[(size_t)row * D + k0 + q * 4];
            sm.st.Ws[q * 4 + 0][NEXP + row] = nv.x;
            sm.st.Ws[q * 4 + 1][NEXP + row] = nv.y;
            sm.st.Ws[q * 4 + 2][NEXP + row] = nv.z;
            sm.st.Ws[q * 4 + 3][NEXP + row] = nv.w;
        }
        __syncthreads();

#pragma unroll 4
        for (int kk = 0; kk < BK; ++kk) {
            const float4 xa = *(const float4*)&sm.st.Xs[kk][r0];
            const float4 xb = *(const float4*)&sm.st.Xs[kk][r0 + 4];
            const float4 wv = *(const float4*)&sm.st.Ws[kk][c0];
            const float xs[8] = {xa.x, xa.y, xa.z, xa.w, xb.x, xb.y, xb.z, xb.w};
            const float ws[4] = {wv.x, wv.y, wv.z, wv.w};
#pragma unroll
            for (int i = 0; i < 8; ++i)
#pragma unroll
                for (int j = 0; j < 4; ++j)
                    acc[i][j] = fmaf(xs[i], ws[j], acc[i][j]);
        }
        __syncthreads();
    }

    // ---- epilogue ----
    // bias + move accumulators to LDS logits buffer (overwrites stage tiles; all
    // compute reads completed before last __syncthreads above)
    {
        const float4 bv = (c0 < NEXP) ? *(const float4*)&br[c0]
                                      : *(const float4*)&bn[c0 - NEXP];
#pragma unroll
        for (int i = 0; i < 8; ++i) {
            float4 o;
            o.x = acc[i][0] + bv.x;
            o.y = acc[i][1] + bv.y;
            o.z = acc[i][2] + bv.z;
            o.w = acc[i][3] + bv.w;
            *(float4*)&sm.L[r0 + i][c0] = o;
        }
    }
    __syncthreads();

    // noisy logits in-place over cols 0..63: noisy = logit + eps * softplus(noise)
#pragma unroll
    for (int t = 0; t < 4; ++t) {
        const int f   = tid * 4 + t * 1024;  // 0..4095 over 64 rows x 64 experts
        const int row = f >> 6;
        const int e0  = f & 63;
        const float4 ev = *(const float4*)&eps[(size_t)(rowbase + row) * NEXP + e0];
        const float evs[4] = {ev.x, ev.y, ev.z, ev.w};
#pragma unroll
        for (int j = 0; j < 4; ++j) {
            const float lg = sm.L[row][e0 + j];
            const float nz = sm.L[row][NEXP + e0 + j];
            sm.L[row][e0 + j] = fmaf(evs[j], softplus_f(nz), lg);
        }
    }
    __syncthreads();

    // per-row top-2 (strict > preserves lower-index-first on ties, matching top_k)
    if (tid < TM) {
        const int r = tid;
        float v1 = -INFINITY, v2 = -INFINITY;
        int i1 = 0, i2 = 0;
#pragma unroll 8
        for (int e = 0; e < NEXP; ++e) {
            const float v = sm.L[r][e];
            if (v > v1) { v2 = v1; i2 = i1; v1 = v; i1 = e; }
            else if (v > v2) { v2 = v; i2 = e; }
        }
        const float z = expf(v2 - v1);     // <= 1, no overflow
        const float s = 1.0f + z;
        p1s[r] = 1.0f / s;
        p2s[r] = z / s;
        i1s[r] = i1;
        i2s[r] = i2;
        // indices output (read back as float32 by harness)
        float* oidx = out + (size_t)N * NEXP + (size_t)(rowbase + r) * 2;
        oidx[0] = (float)i1;
        oidx[1] = (float)i2;
    }
    __syncthreads();

    // sparse-softmax output rows, coalesced: 4 threads per row, 16 floats each
    {
        const int r = tid >> 2;
        const int g = tid & 3;
        const float pa = p1s[r], pb = p2s[r];
        const int i1 = i1s[r], i2 = i2s[r];
        float* orow = out + (size_t)(rowbase + r) * NEXP;
#pragma unroll
        for (int t = 0; t < 4; ++t) {
            const int e0 = g * 16 + t * 4;
            float4 o;
            o.x = (e0 + 0 == i1) ? pa : ((e0 + 0 == i2) ? pb : 0.0f);
            o.y = (e0 + 1 == i1) ? pa : ((e0 + 1 == i2) ? pb : 0.0f);
            o.z = (e0 + 2 == i1) ? pa : ((e0 + 2 == i2) ? pb : 0.0f);
            o.w = (e0 + 3 == i1) ? pa : ((e0 + 3 == i2) ? pb : 0.0f);
            *(float4*)&orow[e0] = o;
        }
    }
}

extern "C" void kernel_launch(void* const* d_in, const int* in_sizes, int n_in,
                              void* d_out, int out_size, void* d_ws, size_t ws_size,
                              hipStream_t stream) {
    const float* x   = (const float*)d_in[0];
    const float* Wr  = (const float*)d_in[1];
    const float* br  = (const float*)d_in[2];
    const float* Wn  = (const float*)d_in[3];
    const float* bn  = (const float*)d_in[4];
    const float* eps = (const float*)d_in[5];
    float* out = (float*)d_out;

    const int E = in_sizes[2];           // 64
    const int D = in_sizes[1] / E;       // 2048
    const int N = in_sizes[0] / D;       // 32768

    dim3 grid(N / TM), block(256);
    noisy_topk_router_kernel<<<grid, block, 0, stream>>>(x, Wr, br, Wn, bn, eps, out, N, D);
}

// Round 2
// 429.682 us; speedup vs baseline: 1.2634x; 1.2634x over previous
//
#include <hip/hip_runtime.h>
#include <math.h>

typedef _Float16 f16;
typedef __attribute__((ext_vector_type(8))) _Float16 half8;
typedef __attribute__((ext_vector_type(4))) float f32x4;

#define NEXP 64
#define TM 64            // rows per block
#define L_STRIDE 132

__device__ __forceinline__ float softplus_f(float x) {
    return fmaxf(x, 0.0f) + log1pf(expf(-fabsf(x)));
}

__device__ __forceinline__ void lds_dma16(const void* g, void* l) {
    __builtin_amdgcn_global_load_lds(
        (const __attribute__((address_space(1))) unsigned int*)g,
        (__attribute__((address_space(3))) unsigned int*)l, 16, 0, 0);
}

// ---------------- pre-kernel: split W (route|noise) into f16 hi/lo planes ----
// ws layout (f16 units): [kc][plane(2)][q(4)][col(128)][8]   (16 KB per kc)
__global__ void wsplit_kernel(const float* __restrict__ Wr,
                              const float* __restrict__ Wn,
                              f16* __restrict__ ws, int D) {
    const int per_col = D >> 3;                       // threads per col (8 k each)
    const int t = blockIdx.x * blockDim.x + threadIdx.x;
    const int col = t / per_col;
    const int k0  = (t - col * per_col) * 8;
    if (col >= 128) return;
    const float* src = (col < NEXP) ? &Wr[(size_t)col * D] : &Wn[(size_t)(col - NEXP) * D];
    const float4 v0 = *(const float4*)&src[k0];
    const float4 v1 = *(const float4*)&src[k0 + 4];
    const float vv[8] = {v0.x, v0.y, v0.z, v0.w, v1.x, v1.y, v1.z, v1.w};
    half8 hi, lo;
#pragma unroll
    for (int j = 0; j < 8; ++j) {
        const f16 h = (f16)vv[j];
        hi[j] = h;
        lo[j] = (f16)((vv[j] - (float)h) * 4096.0f);
    }
    const int kc = k0 >> 5, q = (k0 >> 3) & 3;
    const size_t base = (size_t)kc * 8192 + (size_t)q * 1024 + (size_t)col * 8;
    *(half8*)&ws[base]        = hi;   // plane 0 (hi)
    *(half8*)&ws[base + 4096] = lo;   // plane 1 (lo, pre-scaled 2^12)
}

// ---------------- main kernel: split-f16 MFMA GEMM + fused router epilogue ---
__global__ __launch_bounds__(256, 2)
void router_mfma_kernel(const float* __restrict__ x,
                        const f16* __restrict__ wsW,
                        const float* __restrict__ br,
                        const float* __restrict__ bn,
                        const float* __restrict__ eps,
                        float* __restrict__ out,
                        int N, int D) {
    __shared__ union alignas(16) {
        struct {
            f16 B[2][4][128][8];   // [plane][q][col][8f16]  16 KB
            f16 A[2][4][64][8];    // [plane][q][row][8f16]   8 KB
        } st;
        float L[TM][L_STRIDE];     // logits, 33.8 KB
    } sm;
    __shared__ float biasLDS[128];
    __shared__ float p1s[TM], p2s[TM];
    __shared__ int   i1s[TM], i2s[TM];

    const int tid  = threadIdx.x;
    const int lane = tid & 63;
    const int w    = tid >> 6;
    const int rowbase = blockIdx.x * TM;
    const int wr = w & 1, wc = w >> 1;      // wave tile: 32 rows x 64 cols
    const int quad = lane >> 4;
    const int l16  = lane & 15;

    if (tid < 128) biasLDS[tid] = (tid < NEXP) ? br[tid] : bn[tid - NEXP];

    f32x4 accM[2][4], accC[2][4];
#pragma unroll
    for (int i = 0; i < 2; ++i)
#pragma unroll
        for (int j = 0; j < 4; ++j) {
            accM[i][j] = (f32x4){0.f, 0.f, 0.f, 0.f};
            accC[i][j] = (f32x4){0.f, 0.f, 0.f, 0.f};
        }

    // A staging mapping: thread -> (row, k-group of 8)
    const int sr = tid >> 2;
    const int sq = tid & 3;
    const float* xrow = &x[(size_t)(rowbase + sr) * D + sq * 8];

    const int nkc = D >> 5;
    float4 v0 = *(const float4*)&xrow[0];
    float4 v1 = *(const float4*)&xrow[4];

    for (int kc = 0; kc < nkc; ++kc) {
        // ---- stage B: 16 KB linear copy from ws via lds-dma (4 issues/wave)
        {
            const char* gsrc = (const char*)wsW + (size_t)kc * 16384 + w * 4096 + lane * 16;
            char* ldst = (char*)&sm.st.B[0][0][0][0] + w * 4096;
#pragma unroll
            for (int i = 0; i < 4; ++i)
                lds_dma16(gsrc + i * 1024, ldst + i * 1024);
        }
        // ---- stage A: convert current x regs -> hi/lo planes
        {
            const float vv[8] = {v0.x, v0.y, v0.z, v0.w, v1.x, v1.y, v1.z, v1.w};
            half8 hv, lv;
#pragma unroll
            for (int j = 0; j < 8; ++j) {
                const f16 h = (f16)vv[j];
                hv[j] = h;
                lv[j] = (f16)((vv[j] - (float)h) * 4096.0f);
            }
            *(half8*)&sm.st.A[0][sq][sr][0] = hv;
            *(half8*)&sm.st.A[1][sq][sr][0] = lv;
        }
        __syncthreads();

        // ---- frags
        half8 ah[2], al[2], bh[4], bl[4];
#pragma unroll
        for (int rt = 0; rt < 2; ++rt) {
            ah[rt] = *(const half8*)&sm.st.A[0][quad][wr * 32 + rt * 16 + l16][0];
            al[rt] = *(const half8*)&sm.st.A[1][quad][wr * 32 + rt * 16 + l16][0];
        }
#pragma unroll
        for (int ct = 0; ct < 4; ++ct) {
            bh[ct] = *(const half8*)&sm.st.B[0][quad][wc * 64 + ct * 16 + l16][0];
            bl[ct] = *(const half8*)&sm.st.B[1][quad][wc * 64 + ct * 16 + l16][0];
        }

        // ---- prefetch next x chunk (latency hides behind MFMA phase)
        const int kn = (kc + 1 < nkc) ? kc + 1 : kc;
        v0 = *(const float4*)&xrow[kn * 32];
        v1 = *(const float4*)&xrow[kn * 32 + 4];

        // ---- MFMA: main (hi*hi) + cross (lo_s*hi + hi*lo_s)
#pragma unroll
        for (int rt = 0; rt < 2; ++rt)
#pragma unroll
            for (int ct = 0; ct < 4; ++ct) {
                accM[rt][ct] = __builtin_amdgcn_mfma_f32_16x16x32_f16(ah[rt], bh[ct], accM[rt][ct], 0, 0, 0);
                accC[rt][ct] = __builtin_amdgcn_mfma_f32_16x16x32_f16(al[rt], bh[ct], accC[rt][ct], 0, 0, 0);
                accC[rt][ct] = __builtin_amdgcn_mfma_f32_16x16x32_f16(ah[rt], bl[ct], accC[rt][ct], 0, 0, 0);
            }
        __syncthreads();
    }

    // ---- combine accs + bias -> logits in LDS (C/D: col=lane&15, row=quad*4+reg)
#pragma unroll
    for (int rt = 0; rt < 2; ++rt)
#pragma unroll
        for (int ct = 0; ct < 4; ++ct) {
            const int row = wr * 32 + rt * 16 + quad * 4;
            const int col = wc * 64 + ct * 16 + l16;
            const float bcol = biasLDS[col];
#pragma unroll
            for (int rg = 0; rg < 4; ++rg)
                sm.L[row + rg][col] = accM[rt][ct][rg] + accC[rt][ct][rg] * (1.0f / 4096.0f) + bcol;
        }
    __syncthreads();

    // ---- noisy logits in-place over cols 0..63
#pragma unroll
    for (int t = 0; t < 4; ++t) {
        const int f   = tid * 4 + t * 1024;
        const int row = f >> 6;
        const int e0  = f & 63;
        const float4 ev = *(const float4*)&eps[(size_t)(rowbase + row) * NEXP + e0];
        const float evs[4] = {ev.x, ev.y, ev.z, ev.w};
#pragma unroll
        for (int j = 0; j < 4; ++j) {
            const float lg = sm.L[row][e0 + j];
            const float nz = sm.L[row][NEXP + e0 + j];
            sm.L[row][e0 + j] = fmaf(evs[j], softplus_f(nz), lg);
        }
    }
    __syncthreads();

    // ---- per-row top-2 (strict > = first-occurrence tie-break, matches top_k)
    if (tid < TM) {
        const int r = tid;
        float v1t = -INFINITY, v2t = -INFINITY;
        int i1 = 0, i2 = 0;
#pragma unroll 8
        for (int e = 0; e < NEXP; ++e) {
            const float v = sm.L[r][e];
            if (v > v1t) { v2t = v1t; i2 = i1; v1t = v; i1 = e; }
            else if (v > v2t) { v2t = v; i2 = e; }
        }
        const float z = expf(v2t - v1t);
        const float s = 1.0f + z;
        p1s[r] = 1.0f / s;
        p2s[r] = z / s;
        i1s[r] = i1;
        i2s[r] = i2;
        float* oidx = out + (size_t)N * NEXP + (size_t)(rowbase + r) * 2;
        oidx[0] = (float)i1;
        oidx[1] = (float)i2;
    }
    __syncthreads();

    // ---- sparse-softmax rows, coalesced
    {
        const int r = tid >> 2;
        const int g = tid & 3;
        const float pa = p1s[r], pb = p2s[r];
        const int i1 = i1s[r], i2 = i2s[r];
        float* orow = out + (size_t)(rowbase + r) * NEXP;
#pragma unroll
        for (int t = 0; t < 4; ++t) {
            const int e0 = g * 16 + t * 4;
            float4 o;
            o.x = (e0 + 0 == i1) ? pa : ((e0 + 0 == i2) ? pb : 0.0f);
            o.y = (e0 + 1 == i1) ? pa : ((e0 + 1 == i2) ? pb : 0.0f);
            o.z = (e0 + 2 == i1) ? pa : ((e0 + 2 == i2) ? pb : 0.0f);
            o.w = (e0 + 3 == i1) ? pa : ((e0 + 3 == i2) ? pb : 0.0f);
            *(float4*)&orow[e0] = o;
        }
    }
}

// ---------------- fallback: verified fp32 kernel from R1 ---------------------
#define BK 32
#define XS_STRIDE (TM + 4)
#define WS_STRIDE (128 + 4)

__global__ __launch_bounds__(256, 2)
void noisy_topk_router_kernel(const float* __restrict__ x,
                              const float* __restrict__ Wr,
                              const float* __restrict__ br,
                              const float* __restrict__ Wn,
                              const float* __restrict__ bn,
                              const float* __restrict__ eps,
                              float* __restrict__ out,
                              int N, int D) {
    __shared__ union alignas(16) {
        struct {
            float Xs[BK][XS_STRIDE];
            float Ws[BK][WS_STRIDE];
        } st;
        float L[TM][L_STRIDE];
    } sm;
    __shared__ float p1s[TM], p2s[TM];
    __shared__ int   i1s[TM], i2s[TM];

    const int tid = threadIdx.x;
    const int rowbase = blockIdx.x * TM;
    const int r0 = (tid >> 5) * 8;
    const int c0 = (tid & 31) * 4;

    float acc[8][4];
#pragma unroll
    for (int i = 0; i < 8; ++i)
#pragma unroll
        for (int j = 0; j < 4; ++j) acc[i][j] = 0.0f;

    const int q  = tid & 7;
    const int rr = tid >> 3;

    for (int k0 = 0; k0 < D; k0 += BK) {
#pragma unroll
        for (int i = 0; i < 2; ++i) {
            const int row = rr + 32 * i;
            const float4 xv = *(const float4*)&x[(size_t)(rowbase + row) * D + k0 + q * 4];
            sm.st.Xs[q * 4 + 0][row] = xv.x;
            sm.st.Xs[q * 4 + 1][row] = xv.y;
            sm.st.Xs[q * 4 + 2][row] = xv.z;
            sm.st.Xs[q * 4 + 3][row] = xv.w;
            const float4 wv = *(const float4*)&Wr[(size_t)row * D + k0 + q * 4];
            sm.st.Ws[q * 4 + 0][row] = wv.x;
            sm.st.Ws[q * 4 + 1][row] = wv.y;
            sm.st.Ws[q * 4 + 2][row] = wv.z;
            sm.st.Ws[q * 4 + 3][row] = wv.w;
            const float4 nv = *(const float4*)&Wn[(size_t)row * D + k0 + q * 4];
            sm.st.Ws[q * 4 + 0][NEXP + row] = nv.x;
            sm.st.Ws[q * 4 + 1][NEXP + row] = nv.y;
            sm.st.Ws[q * 4 + 2][NEXP + row] = nv.z;
            sm.st.Ws[q * 4 + 3][NEXP + row] = nv.w;
        }
        __syncthreads();
#pragma unroll 4
        for (int kk = 0; kk < BK; ++kk) {
            const float4 xa = *(const float4*)&sm.st.Xs[kk][r0];
            const float4 xb = *(const float4*)&sm.st.Xs[kk][r0 + 4];
            const float4 wv = *(const float4*)&sm.st.Ws[kk][c0];
            const float xs[8] = {xa.x, xa.y, xa.z, xa.w, xb.x, xb.y, xb.z, xb.w};
            const float ws[4] = {wv.x, wv.y, wv.z, wv.w};
#pragma unroll
            for (int i = 0; i < 8; ++i)
#pragma unroll
                for (int j = 0; j < 4; ++j)
                    acc[i][j] = fmaf(xs[i], ws[j], acc[i][j]);
        }
        __syncthreads();
    }
    {
        const float4 bv = (c0 < NEXP) ? *(const float4*)&br[c0]
                                      : *(const float4*)&bn[c0 - NEXP];
#pragma unroll
        for (int i = 0; i < 8; ++i) {
            float4 o;
            o.x = acc[i][0] + bv.x;
            o.y = acc[i][1] + bv.y;
            o.z = acc[i][2] + bv.z;
            o.w = acc[i][3] + bv.w;
            *(float4*)&sm.L[r0 + i][c0] = o;
        }
    }
    __syncthreads();
#pragma unroll
    for (int t = 0; t < 4; ++t) {
        const int f   = tid * 4 + t * 1024;
        const int row = f >> 6;
        const int e0  = f & 63;
        const float4 ev = *(const float4*)&eps[(size_t)(rowbase + row) * NEXP + e0];
        const float evs[4] = {ev.x, ev.y, ev.z, ev.w};
#pragma unroll
        for (int j = 0; j < 4; ++j) {
            const float lg = sm.L[row][e0 + j];
            const float nz = sm.L[row][NEXP + e0 + j];
            sm.L[row][e0 + j] = fmaf(evs[j], softplus_f(nz), lg);
        }
    }
    __syncthreads();
    if (tid < TM) {
        const int r = tid;
        float v1 = -INFINITY, v2 = -INFINITY;
        int i1 = 0, i2 = 0;
#pragma unroll 8
        for (int e = 0; e < NEXP; ++e) {
            const float v = sm.L[r][e];
            if (v > v1) { v2 = v1; i2 = i1; v1 = v; i1 = e; }
            else if (v > v2) { v2 = v; i2 = e; }
        }
        const float z = expf(v2 - v1);
        const float s = 1.0f + z;
        p1s[r] = 1.0f / s;
        p2s[r] = z / s;
        i1s[r] = i1;
        i2s[r] = i2;
        float* oidx = out + (size_t)N * NEXP + (size_t)(rowbase + r) * 2;
        oidx[0] = (float)i1;
        oidx[1] = (float)i2;
    }
    __syncthreads();
    {
        const int r = tid >> 2;
        const int g = tid & 3;
        const float pa = p1s[r], pb = p2s[r];
        const int i1 = i1s[r], i2 = i2s[r];
        float* orow = out + (size_t)(rowbase + r) * NEXP;
#pragma unroll
        for (int t = 0; t < 4; ++t) {
            const int e0 = g * 16 + t * 4;
            float4 o;
            o.x = (e0 + 0 == i1) ? pa : ((e0 + 0 == i2) ? pb : 0.0f);
            o.y = (e0 + 1 == i1) ? pa : ((e0 + 1 == i2) ? pb : 0.0f);
            o.z = (e0 + 2 == i1) ? pa : ((e0 + 2 == i2) ? pb : 0.0f);
            o.w = (e0 + 3 == i1) ? pa : ((e0 + 3 == i2) ? pb : 0.0f);
            *(float4*)&orow[e0] = o;
        }
    }
}

extern "C" void kernel_launch(void* const* d_in, const int* in_sizes, int n_in,
                              void* d_out, int out_size, void* d_ws, size_t ws_size,
                              hipStream_t stream) {
    const float* x   = (const float*)d_in[0];
    const float* Wr  = (const float*)d_in[1];
    const float* br  = (const float*)d_in[2];
    const float* Wn  = (const float*)d_in[3];
    const float* bn  = (const float*)d_in[4];
    const float* eps = (const float*)d_in[5];
    float* out = (float*)d_out;

    const int E = in_sizes[2];
    const int D = in_sizes[1] / E;
    const int N = in_sizes[0] / D;

    const size_t ws_needed = (size_t)128 * D * 2 * sizeof(f16);  // 1 MB at D=2048
    const bool fast = (E == 64) && (D == 2048) && (N % TM == 0) && (ws_size >= ws_needed);

    if (fast) {
        const int pre_threads = 128 * (D / 8);
        wsplit_kernel<<<(pre_threads + 255) / 256, 256, 0, stream>>>(Wr, Wn, (f16*)d_ws, D);
        router_mfma_kernel<<<N / TM, 256, 0, stream>>>(x, (const f16*)d_ws, br, bn, eps, out, N, D);
    } else {
        noisy_topk_router_kernel<<<N / TM, 256, 0, stream>>>(x, Wr, br, Wn, bn, eps, out, N, D);
    }
}

// Round 3
// 428.952 us; speedup vs baseline: 1.2655x; 1.0017x over previous
//
#include <hip/hip_runtime.h>
#include <math.h>

typedef _Float16 f16;
typedef __attribute__((ext_vector_type(8))) _Float16 half8;
typedef __attribute__((ext_vector_type(4))) float f32x4;

#define NEXP 64
#define TM 64
#define L_STRIDE 132

__device__ __forceinline__ float softplus_f(float x) {
    return fmaxf(x, 0.0f) + log1pf(expf(-fabsf(x)));
}

__device__ __forceinline__ void lds_dma16(const void* g, void* l) {
    __builtin_amdgcn_global_load_lds(
        (const __attribute__((address_space(1))) unsigned int*)g,
        (__attribute__((address_space(3))) unsigned int*)l, 16, 0, 0);
}

__device__ __forceinline__ void cvt_split(const float4 a, const float4 b,
                                          half8& hv, half8& lv) {
    const float vv[8] = {a.x, a.y, a.z, a.w, b.x, b.y, b.z, b.w};
#pragma unroll
    for (int j = 0; j < 8; ++j) {
        const f16 h = (f16)vv[j];
        hv[j] = h;
        lv[j] = (f16)((vv[j] - (float)h) * 4096.0f);
    }
}

// ---------------- pre-kernel: split W (route|noise) into f16 hi/lo planes ----
// ws layout (f16 units): [kc][plane(2)][q(4)][col(128)][8]   (16 KB per kc)
__global__ void wsplit_kernel(const float* __restrict__ Wr,
                              const float* __restrict__ Wn,
                              f16* __restrict__ ws, int D) {
    const int per_col = D >> 3;
    const int t = blockIdx.x * blockDim.x + threadIdx.x;
    const int col = t / per_col;
    const int k0  = (t - col * per_col) * 8;
    if (col >= 128) return;
    const float* src = (col < NEXP) ? &Wr[(size_t)col * D] : &Wn[(size_t)(col - NEXP) * D];
    const float4 v0 = *(const float4*)&src[k0];
    const float4 v1 = *(const float4*)&src[k0 + 4];
    half8 hi, lo;
    cvt_split(v0, v1, hi, lo);
    const int kc = k0 >> 5, q = (k0 >> 3) & 3;
    const size_t base = (size_t)kc * 8192 + (size_t)q * 1024 + (size_t)col * 8;
    *(half8*)&ws[base]        = hi;
    *(half8*)&ws[base + 4096] = lo;
}

// ---------------- main kernel: split-f16 MFMA GEMM, double-buffered ----------
__global__ __launch_bounds__(256, 3)
void router_mfma_kernel(const float* __restrict__ x,
                        const f16* __restrict__ wsW,
                        const float* __restrict__ br,
                        const float* __restrict__ bn,
                        const float* __restrict__ eps,
                        float* __restrict__ out,
                        int N, int D) {
    // st.B[buf]: [plane][q][col][8] f16 = 16 KB/buf; st.A[buf]: [plane][q][row][8] = 8 KB/buf
    __shared__ union alignas(16) {
        struct { f16 B[2][8192]; f16 A[2][4096]; } st;   // 48 KB
        float L[TM][L_STRIDE];                            // 33.8 KB
    } sm;
    __shared__ float biasLDS[128];
    __shared__ float p1s[TM], p2s[TM];
    __shared__ int   i1s[TM], i2s[TM];

    const int tid  = threadIdx.x;
    const int lane = tid & 63;
    const int w    = tid >> 6;
    const int rowbase = blockIdx.x * TM;
    const int wr = w & 1, wc = w >> 1;     // wave tile: 32 rows x 64 cols
    const int quad = lane >> 4;
    const int l16  = lane & 15;

    if (tid < 128) biasLDS[tid] = (tid < NEXP) ? br[tid] : bn[tid - NEXP];

    f32x4 accM[2][4], accC[2][4];
#pragma unroll
    for (int i = 0; i < 2; ++i)
#pragma unroll
        for (int j = 0; j < 4; ++j) {
            accM[i][j] = (f32x4){0.f, 0.f, 0.f, 0.f};
            accC[i][j] = (f32x4){0.f, 0.f, 0.f, 0.f};
        }

    // x staging mapping: row sr (0..63), k-group sq (0..3) -> 32B per thread/iter
    const int sr = tid >> 2;
    const int sq = tid & 3;
    const float* xrow = &x[(size_t)(rowbase + sr) * D + sq * 8];
    const int nkc = D >> 5;   // 64

    // ---- prologue: stage kc=0, prefetch chunk 1
    {
        const char* gsrc = (const char*)wsW + (size_t)0 * 16384 + w * 4096 + lane * 16;
        char* ldst = (char*)&sm.st.B[0][0] + w * 4096;
#pragma unroll
        for (int i = 0; i < 4; ++i) lds_dma16(gsrc + i * 1024, ldst + i * 1024);
        const float4 a0 = *(const float4*)&xrow[0];
        const float4 a1 = *(const float4*)&xrow[4];
        half8 hv, lv;
        cvt_split(a0, a1, hv, lv);
        *(half8*)&sm.st.A[0][sq * 512 + sr * 8]        = hv;
        *(half8*)&sm.st.A[0][2048 + sq * 512 + sr * 8] = lv;
    }
    float4 v0 = *(const float4*)&xrow[32];
    float4 v1 = *(const float4*)&xrow[36];
    __syncthreads();

#pragma unroll 2
    for (int kc = 0; kc < nkc; ++kc) {
        const int cur = kc & 1, nxt = cur ^ 1;

        // ---- issue next B-tile DMA first (longest queue age before drain)
        if (kc + 1 < nkc) {
            const char* gsrc = (const char*)wsW + (size_t)(kc + 1) * 16384 + w * 4096 + lane * 16;
            char* ldst = (char*)&sm.st.B[nxt][0] + w * 4096;
#pragma unroll
            for (int i = 0; i < 4; ++i) lds_dma16(gsrc + i * 1024, ldst + i * 1024);
            // ---- convert chunk kc+1 (loaded a full iter ago) into A[nxt]
            half8 hv, lv;
            cvt_split(v0, v1, hv, lv);
            *(half8*)&sm.st.A[nxt][sq * 512 + sr * 8]        = hv;
            *(half8*)&sm.st.A[nxt][2048 + sq * 512 + sr * 8] = lv;
        }
        // ---- prefetch chunk kc+2 into registers
        if (kc + 2 < nkc) {
            v0 = *(const float4*)&xrow[(kc + 2) * 32];
            v1 = *(const float4*)&xrow[(kc + 2) * 32 + 4];
        }

        // ---- fragments from current buffers
        half8 ah[2], al[2], bh[4], bl[4];
#pragma unroll
        for (int rt = 0; rt < 2; ++rt) {
            const int r = (wr * 32 + rt * 16 + l16) * 8;
            ah[rt] = *(const half8*)&sm.st.A[cur][quad * 512 + r];
            al[rt] = *(const half8*)&sm.st.A[cur][2048 + quad * 512 + r];
        }
#pragma unroll
        for (int ct = 0; ct < 4; ++ct) {
            const int c = (wc * 64 + ct * 16 + l16) * 8;
            bh[ct] = *(const half8*)&sm.st.B[cur][quad * 1024 + c];
            bl[ct] = *(const half8*)&sm.st.B[cur][4096 + quad * 1024 + c];
        }

#pragma unroll
        for (int rt = 0; rt < 2; ++rt)
#pragma unroll
            for (int ct = 0; ct < 4; ++ct) {
                accM[rt][ct] = __builtin_amdgcn_mfma_f32_16x16x32_f16(ah[rt], bh[ct], accM[rt][ct], 0, 0, 0);
                accC[rt][ct] = __builtin_amdgcn_mfma_f32_16x16x32_f16(al[rt], bh[ct], accC[rt][ct], 0, 0, 0);
                accC[rt][ct] = __builtin_amdgcn_mfma_f32_16x16x32_f16(ah[rt], bl[ct], accC[rt][ct], 0, 0, 0);
            }
        __syncthreads();
    }

    // ---- combine accs + bias -> logits in LDS (C/D: col=lane&15, row=quad*4+reg)
#pragma unroll
    for (int rt = 0; rt < 2; ++rt)
#pragma unroll
        for (int ct = 0; ct < 4; ++ct) {
            const int row = wr * 32 + rt * 16 + quad * 4;
            const int col = wc * 64 + ct * 16 + l16;
            const float bcol = biasLDS[col];
#pragma unroll
            for (int rg = 0; rg < 4; ++rg)
                sm.L[row + rg][col] = accM[rt][ct][rg] + accC[rt][ct][rg] * (1.0f / 4096.0f) + bcol;
        }
    __syncthreads();

    // ---- noisy logits in-place over cols 0..63
#pragma unroll
    for (int t = 0; t < 4; ++t) {
        const int f   = tid * 4 + t * 1024;
        const int row = f >> 6;
        const int e0  = f & 63;
        const float4 ev = *(const float4*)&eps[(size_t)(rowbase + row) * NEXP + e0];
        const float evs[4] = {ev.x, ev.y, ev.z, ev.w};
#pragma unroll
        for (int j = 0; j < 4; ++j) {
            const float lg = sm.L[row][e0 + j];
            const float nz = sm.L[row][NEXP + e0 + j];
            sm.L[row][e0 + j] = fmaf(evs[j], softplus_f(nz), lg);
        }
    }
    __syncthreads();

    // ---- per-row top-2 (strict > = first-occurrence tie-break, matches top_k)
    if (tid < TM) {
        const int r = tid;
        float v1t = -INFINITY, v2t = -INFINITY;
        int i1 = 0, i2 = 0;
#pragma unroll 8
        for (int e = 0; e < NEXP; ++e) {
            const float v = sm.L[r][e];
            if (v > v1t) { v2t = v1t; i2 = i1; v1t = v; i1 = e; }
            else if (v > v2t) { v2t = v; i2 = e; }
        }
        const float z = expf(v2t - v1t);
        const float s = 1.0f + z;
        p1s[r] = 1.0f / s;
        p2s[r] = z / s;
        i1s[r] = i1;
        i2s[r] = i2;
        float* oidx = out + (size_t)N * NEXP + (size_t)(rowbase + r) * 2;
        oidx[0] = (float)i1;
        oidx[1] = (float)i2;
    }
    __syncthreads();

    // ---- sparse-softmax rows, coalesced
    {
        const int r = tid >> 2;
        const int g = tid & 3;
        const float pa = p1s[r], pb = p2s[r];
        const int i1 = i1s[r], i2 = i2s[r];
        float* orow = out + (size_t)(rowbase + r) * NEXP;
#pragma unroll
        for (int t = 0; t < 4; ++t) {
            const int e0 = g * 16 + t * 4;
            float4 o;
            o.x = (e0 + 0 == i1) ? pa : ((e0 + 0 == i2) ? pb : 0.0f);
            o.y = (e0 + 1 == i1) ? pa : ((e0 + 1 == i2) ? pb : 0.0f);
            o.z = (e0 + 2 == i1) ? pa : ((e0 + 2 == i2) ? pb : 0.0f);
            o.w = (e0 + 3 == i1) ? pa : ((e0 + 3 == i2) ? pb : 0.0f);
            *(float4*)&orow[e0] = o;
        }
    }
}

// ---------------- fallback: verified fp32 kernel from R1 ---------------------
#define BK 32
#define XS_STRIDE (TM + 4)
#define WS_STRIDE (128 + 4)

__global__ __launch_bounds__(256, 2)
void noisy_topk_router_kernel(const float* __restrict__ x,
                              const float* __restrict__ Wr,
                              const float* __restrict__ br,
                              const float* __restrict__ Wn,
                              const float* __restrict__ bn,
                              const float* __restrict__ eps,
                              float* __restrict__ out,
                              int N, int D) {
    __shared__ union alignas(16) {
        struct {
            float Xs[BK][XS_STRIDE];
            float Ws[BK][WS_STRIDE];
        } st;
        float L[TM][L_STRIDE];
    } sm;
    __shared__ float p1s[TM], p2s[TM];
    __shared__ int   i1s[TM], i2s[TM];

    const int tid = threadIdx.x;
    const int rowbase = blockIdx.x * TM;
    const int r0 = (tid >> 5) * 8;
    const int c0 = (tid & 31) * 4;

    float acc[8][4];
#pragma unroll
    for (int i = 0; i < 8; ++i)
#pragma unroll
        for (int j = 0; j < 4; ++j) acc[i][j] = 0.0f;

    const int q  = tid & 7;
    const int rr = tid >> 3;

    for (int k0 = 0; k0 < D; k0 += BK) {
#pragma unroll
        for (int i = 0; i < 2; ++i) {
            const int row = rr + 32 * i;
            const float4 xv = *(const float4*)&x[(size_t)(rowbase + row) * D + k0 + q * 4];
            sm.st.Xs[q * 4 + 0][row] = xv.x;
            sm.st.Xs[q * 4 + 1][row] = xv.y;
            sm.st.Xs[q * 4 + 2][row] = xv.z;
            sm.st.Xs[q * 4 + 3][row] = xv.w;
            const float4 wv = *(const float4*)&Wr[(size_t)row * D + k0 + q * 4];
            sm.st.Ws[q * 4 + 0][row] = wv.x;
            sm.st.Ws[q * 4 + 1][row] = wv.y;
            sm.st.Ws[q * 4 + 2][row] = wv.z;
            sm.st.Ws[q * 4 + 3][row] = wv.w;
            const float4 nv = *(const float4*)&Wn[(size_t)row * D + k0 + q * 4];
            sm.st.Ws[q * 4 + 0][NEXP + row] = nv.x;
            sm.st.Ws[q * 4 + 1][NEXP + row] = nv.y;
            sm.st.Ws[q * 4 + 2][NEXP + row] = nv.z;
            sm.st.Ws[q * 4 + 3][NEXP + row] = nv.w;
        }
        __syncthreads();
#pragma unroll 4
        for (int kk = 0; kk < BK; ++kk) {
            const float4 xa = *(const float4*)&sm.st.Xs[kk][r0];
            const float4 xb = *(const float4*)&sm.st.Xs[kk][r0 + 4];
            const float4 wv = *(const float4*)&sm.st.Ws[kk][c0];
            const float xs[8] = {xa.x, xa.y, xa.z, xa.w, xb.x, xb.y, xb.z, xb.w};
            const float ws[4] = {wv.x, wv.y, wv.z, wv.w};
#pragma unroll
            for (int i = 0; i < 8; ++i)
#pragma unroll
                for (int j = 0; j < 4; ++j)
                    acc[i][j] = fmaf(xs[i], ws[j], acc[i][j]);
        }
        __syncthreads();
    }
    {
        const float4 bv = (c0 < NEXP) ? *(const float4*)&br[c0]
                                      : *(const float4*)&bn[c0 - NEXP];
#pragma unroll
        for (int i = 0; i < 8; ++i) {
            float4 o;
            o.x = acc[i][0] + bv.x;
            o.y = acc[i][1] + bv.y;
            o.z = acc[i][2] + bv.z;
            o.w = acc[i][3] + bv.w;
            *(float4*)&sm.L[r0 + i][c0] = o;
        }
    }
    __syncthreads();
#pragma unroll
    for (int t = 0; t < 4; ++t) {
        const int f   = tid * 4 + t * 1024;
        const int row = f >> 6;
        const int e0  = f & 63;
        const float4 ev = *(const float4*)&eps[(size_t)(rowbase + row) * NEXP + e0];
        const float evs[4] = {ev.x, ev.y, ev.z, ev.w};
#pragma unroll
        for (int j = 0; j < 4; ++j) {
            const float lg = sm.L[row][e0 + j];
            const float nz = sm.L[row][NEXP + e0 + j];
            sm.L[row][e0 + j] = fmaf(evs[j], softplus_f(nz), lg);
        }
    }
    __syncthreads();
    if (tid < TM) {
        const int r = tid;
        float v1 = -INFINITY, v2 = -INFINITY;
        int i1 = 0, i2 = 0;
#pragma unroll 8
        for (int e = 0; e < NEXP; ++e) {
            const float v = sm.L[r][e];
            if (v > v1) { v2 = v1; i2 = i1; v1 = v; i1 = e; }
            else if (v > v2) { v2 = v; i2 = e; }
        }
        const float z = expf(v2 - v1);
        const float s = 1.0f + z;
        p1s[r] = 1.0f / s;
        p2s[r] = z / s;
        i1s[r] = i1;
        i2s[r] = i2;
        float* oidx = out + (size_t)N * NEXP + (size_t)(rowbase + r) * 2;
        oidx[0] = (float)i1;
        oidx[1] = (float)i2;
    }
    __syncthreads();
    {
        const int r = tid >> 2;
        const int g = tid & 3;
        const float pa = p1s[r], pb = p2s[r];
        const int i1 = i1s[r], i2 = i2s[r];
        float* orow = out + (size_t)(rowbase + r) * NEXP;
#pragma unroll
        for (int t = 0; t < 4; ++t) {
            const int e0 = g * 16 + t * 4;
            float4 o;
            o.x = (e0 + 0 == i1) ? pa : ((e0 + 0 == i2) ? pb : 0.0f);
            o.y = (e0 + 1 == i1) ? pa : ((e0 + 1 == i2) ? pb : 0.0f);
            o.z = (e0 + 2 == i1) ? pa : ((e0 + 2 == i2) ? pb : 0.0f);
            o.w = (e0 + 3 == i1) ? pa : ((e0 + 3 == i2) ? pb : 0.0f);
            *(float4*)&orow[e0] = o;
        }
    }
}

extern "C" void kernel_launch(void* const* d_in, const int* in_sizes, int n_in,
                              void* d_out, int out_size, void* d_ws, size_t ws_size,
                              hipStream_t stream) {
    const float* x   = (const float*)d_in[0];
    const float* Wr  = (const float*)d_in[1];
    const float* br  = (const float*)d_in[2];
    const float* Wn  = (const float*)d_in[3];
    const float* bn  = (const float*)d_in[4];
    const float* eps = (const float*)d_in[5];
    float* out = (float*)d_out;

    const int E = in_sizes[2];
    const int D = in_sizes[1] / E;
    const int N = in_sizes[0] / D;

    const size_t ws_needed = (size_t)128 * D * 2 * sizeof(f16);
    const bool fast = (E == 64) && (D == 2048) && (N % TM == 0) && (ws_size >= ws_needed);

    if (fast) {
        const int pre_threads = 128 * (D / 8);
        wsplit_kernel<<<(pre_threads + 255) / 256, 256, 0, stream>>>(Wr, Wn, (f16*)d_ws, D);
        router_mfma_kernel<<<N / TM, 256, 0, stream>>>(x, (const f16*)d_ws, br, bn, eps, out, N, D);
    } else {
        noisy_topk_router_kernel<<<N / TM, 256, 0, stream>>>(x, Wr, br, Wn, bn, eps, out, N, D);
    }
}